// Round 4
// baseline (261.535 us; speedup 1.0000x reference)
//
#include <hip/hip_runtime.h>
#include <hip/hip_bf16.h>

#define TT 512
#define II 46
#define HH 64
#define GG 192
#define CC 8
#define RR 4     // rows per block (2 blocks per CU)

typedef __attribute__((ext_vector_type(8))) _Float16 half8;
typedef __attribute__((ext_vector_type(4))) float float4v;

__device__ inline float fsigm(float xv) {
  return __builtin_amdgcn_rcpf(1.f + __expf(-xv));
}
// tanh(x) = 1 - 2/(1 + e^{2x}); saturates correctly at +-1, branch-free
__device__ inline float ftanh2(float xv) {
  float e = __expf(2.f * xv);
  float uu = __builtin_amdgcn_rcpf(1.f + e);
  return __builtin_fmaf(-2.f, uu, 1.f);
}

// Pack fp32 weights into f16 MFMA-B-ready rows: wph[g][k]=w_hh[g][k] (k<64),
// wpx[g][k]=w_ih[g][k] for k<46 else 0 (K padded to 64).
__global__ void pack_w(const float* __restrict__ w_ih, const float* __restrict__ w_hh,
                       _Float16* __restrict__ wph, _Float16* __restrict__ wpx) {
  int idx = blockIdx.x * 256 + threadIdx.x;  // 24576 total
  if (idx < GG * HH) {
    wph[idx] = (_Float16)w_hh[idx];
  } else {
    idx -= GG * HH;
    if (idx < GG * 64) {
      int g = idx >> 6, k = idx & 63;
      wpx[idx] = (_Float16)(k < II ? w_ih[g * II + k] : 0.f);
    }
  }
}

// LDS layouts (fragment-order, f16):
//  hsf[buf][s][64][8]: A-frag for h-GEMM; lane l kstep s reads hsf[buf][s][l][0..7]
//    element h[row][unit k]: s=k>>5, kgrp=(k>>3)&3, j=k&7, line=kgrp*16+row
//  xsf[buf][s][64][8]: same for x (k<46 real, rest zero; rows>=RR stay zero)
//  gxpT[buf][gate][unit 64][row pad 12] f32: x*W_ih^T + biases, transposed
__launch_bounds__(512, 4)
__global__ void gru_main(const float* __restrict__ x,
                         const float* __restrict__ b_ih, const float* __restrict__ b_hh,
                         const float* __restrict__ fc_w, const float* __restrict__ fc_b,
                         const _Float16* __restrict__ wph,
                         const _Float16* __restrict__ wpx,
                         float* __restrict__ out) {
  __shared__ __align__(16) _Float16 hsf[2][2][64][8];
  __shared__ __align__(16) _Float16 xsf[2][2][64][8];
  __shared__ __align__(16) float gxpT[2][3][64][12];
  __shared__ float hf[8][HH + 1];          // rows 4..7 absorb garbage-lane writes
  __shared__ float fcw[CC * HH];
  __shared__ float fcbs[CC];
  __shared__ float lgts[RR][CC];

  const int tau = threadIdx.x;
  const int w8  = tau >> 6;   // wave 0..7
  const int l   = tau & 63;
  const int m16 = l & 15;
  const int kg  = l >> 4;
  const int row0 = blockIdx.x * RR;

  {
    _Float16* hz = &hsf[0][0][0][0];
    for (int i = tau; i < 2 * 2 * 64 * 8; i += 512) hz[i] = (_Float16)0.f;
    _Float16* xz = &xsf[0][0][0][0];
    for (int i = tau; i < 2 * 2 * 64 * 8; i += 512) xz[i] = (_Float16)0.f;
  }
  __syncthreads();  // init fence

  float hreg[2] = {0.f, 0.f};
  // final-owner rows for this lane after the e=2,3 shuffle:
  const int row0l = (kg & 1) * 4 + ((kg >> 1) & 1) * 2;

  if (w8 < 4) {
    // ================= CONSUMER: h-recurrence =================
    const int u = 16 * w8 + m16;       // gate unit owned by this lane
    const float bnh = b_hh[128 + u];
    half8 bh[3][2];
    {
      const int gbs[3] = {16 * w8, 64 + 16 * w8, 128 + 16 * w8};
#pragma unroll
      for (int tt = 0; tt < 3; ++tt) {
        const _Float16* bb = wph + (size_t)(gbs[tt] + m16) * 64 + kg * 8;
        bh[tt][0] = *(const half8*)(bb);
        bh[tt][1] = *(const half8*)(bb + 32);
      }
    }
    // h-write target for unit u, rows row0l+i
    const int sh  = w8 >> 1;
    const int kgp = (u >> 3) & 3;
    const int jp  = u & 7;
    const bool lo2 = (kg < 2);

    __syncthreads();  // prologue sync
    __builtin_amdgcn_s_setprio(1);

    for (int t = 0; t < TT; ++t) {
      __syncthreads();
      const int cur = t & 1, nxt = cur ^ 1;
      half8 a0 = *(const half8*)&hsf[cur][0][l][0];
      half8 a1 = *(const half8*)&hsf[cur][1][l][0];
      // owner-layout gx reads: issued early, consumed after MFMA+shuffle
      float2 gR = *(const float2*)&gxpT[cur][0][u][row0l];
      float2 gZ = *(const float2*)&gxpT[cur][1][u][row0l];
      float2 gN = *(const float2*)&gxpT[cur][2][u][row0l];

      float4v accr = {0.f, 0.f, 0.f, 0.f};
      float4v accz = {0.f, 0.f, 0.f, 0.f};
      float4v accn = {bnh, bnh, bnh, bnh};
      accr = __builtin_amdgcn_mfma_f32_16x16x32_f16(a0, bh[0][0], accr, 0, 0, 0);
      accz = __builtin_amdgcn_mfma_f32_16x16x32_f16(a0, bh[1][0], accz, 0, 0, 0);
      accn = __builtin_amdgcn_mfma_f32_16x16x32_f16(a0, bh[2][0], accn, 0, 0, 0);
      accr = __builtin_amdgcn_mfma_f32_16x16x32_f16(a1, bh[0][1], accr, 0, 0, 0);
      accz = __builtin_amdgcn_mfma_f32_16x16x32_f16(a1, bh[1][1], accz, 0, 0, 0);
      accn = __builtin_amdgcn_mfma_f32_16x16x32_f16(a1, bh[2][1], accn, 0, 0, 0);

      // redistribute rows 2,3 (mod 4) to the kg>=2 lanes
      float r2 = __shfl_xor(accr[2], 32), r3 = __shfl_xor(accr[3], 32);
      float z2 = __shfl_xor(accz[2], 32), z3 = __shfl_xor(accz[3], 32);
      float n2 = __shfl_xor(accn[2], 32), n3 = __shfl_xor(accn[3], 32);
      float aR[2] = {lo2 ? accr[0] : r2, lo2 ? accr[1] : r3};
      float aZ[2] = {lo2 ? accz[0] : z2, lo2 ? accz[1] : z3};
      float aN[2] = {lo2 ? accn[0] : n2, lo2 ? accn[1] : n3};
      float gr[2] = {gR.x, gR.y}, gz[2] = {gZ.x, gZ.y}, gn[2] = {gN.x, gN.y};

#pragma unroll
      for (int i = 0; i < 2; ++i) {
        float rg = fsigm(aR[i] + gr[i]);
        float zg = fsigm(aZ[i] + gz[i]);
        float pre = __builtin_fmaf(rg, aN[i], gn[i]);
        float ng = ftanh2(pre);
        hreg[i] = ng + zg * (hreg[i] - ng);
        hsf[nxt][sh][kgp * 16 + row0l + i][jp] = (_Float16)hreg[i];
      }
    }
    __builtin_amdgcn_s_setprio(0);
  } else {
    // ================= PRODUCER: gxpT(t) = x(t)*W_ih^T + biases =================
    const int wp = w8 - 4;
    const int u = 16 * wp + m16;
    const float br = b_ih[u] + b_hh[u];
    const float bz = b_ih[64 + u] + b_hh[64 + u];
    const float bn = b_ih[128 + u];
    half8 bx[3][2];
    {
      const int gbs[3] = {16 * wp, 64 + 16 * wp, 128 + 16 * wp};
#pragma unroll
      for (int tt = 0; tt < 3; ++tt) {
        const _Float16* bb = wpx + (size_t)(gbs[tt] + m16) * 64 + kg * 8;
        bx[tt][0] = *(const half8*)(bb);
        bx[tt][1] = *(const half8*)(bb + 32);
      }
    }
    const bool wr = (kg < 2);

    // x staging: thread owns element p of the RR x II slab (184 active)
    const int p = tau - 256;
    const bool hasx = p < RR * II;
    const int r1 = hasx ? (p / II) : 0;
    const int i1 = hasx ? (p % II) : 0;
    const float* xp1 = x + (size_t)(row0 + r1) * TT * II + i1;
    const int s1 = i1 >> 5, kg1 = (i1 >> 3) & 3, j1 = i1 & 7;

    auto stageX = [&](int buf, float va) {
      if (hasx) xsf[buf][s1][kg1 * 16 + r1][j1] = (_Float16)va;
    };
    auto produceGx = [&](int buf) {
      half8 a0 = *(const half8*)&xsf[buf][0][l][0];
      half8 a1 = *(const half8*)&xsf[buf][1][l][0];
      float4v ar = {br, br, br, br};
      float4v az = {bz, bz, bz, bz};
      float4v an = {bn, bn, bn, bn};
      ar = __builtin_amdgcn_mfma_f32_16x16x32_f16(a0, bx[0][0], ar, 0, 0, 0);
      az = __builtin_amdgcn_mfma_f32_16x16x32_f16(a0, bx[1][0], az, 0, 0, 0);
      an = __builtin_amdgcn_mfma_f32_16x16x32_f16(a0, bx[2][0], an, 0, 0, 0);
      ar = __builtin_amdgcn_mfma_f32_16x16x32_f16(a1, bx[0][1], ar, 0, 0, 0);
      az = __builtin_amdgcn_mfma_f32_16x16x32_f16(a1, bx[1][1], az, 0, 0, 0);
      an = __builtin_amdgcn_mfma_f32_16x16x32_f16(a1, bx[2][1], an, 0, 0, 0);
      if (wr) {
        *(float4v*)&gxpT[buf][0][u][kg * 4] = ar;
        *(float4v*)&gxpT[buf][1][u][kg * 4] = az;
        *(float4v*)&gxpT[buf][2][u][kg * 4] = an;
      }
    };

    // prologue: load x(0),x(1),x(2); stage x(0); produce gx(0); stage x(1)
    float v0a = hasx ? xp1[0] : 0.f;
    float v1a = hasx ? xp1[II] : 0.f;
    float xc1 = hasx ? xp1[2 * II] : 0.f;
    stageX(0, v0a);
    __syncthreads();  // prologue sync
    produceGx(0);
    stageX(1, v1a);

    for (int t = 0; t < TT; ++t) {
      __syncthreads();
      float nx1 = 0.f;
      if (hasx && t + 3 < TT) nx1 = xp1[(size_t)(t + 3) * II];
      if (t + 1 < TT) produceGx((t + 1) & 1);   // gx(t+1) from xsf[(t+1)&1]
      if (t + 2 < TT) stageX(t & 1, xc1);       // xsf[t&1] = x(t+2)
      xc1 = nx1;
    }
  }

  // ================= Epilogue: FC + softmax =================
  if (w8 < 4) {
    hf[row0l + 0][16 * w8 + m16] = hreg[0];
    hf[row0l + 1][16 * w8 + m16] = hreg[1];
  }
  fcw[tau] = fc_w[tau];  // tau < 512 == CC*HH
  if (tau < CC) fcbs[tau] = fc_b[tau];
  __syncthreads();
  if (tau < RR * CC) {
    int rr = tau >> 3, c = tau & 7;
    float acc = fcbs[c];
#pragma unroll
    for (int j = 0; j < HH; ++j) acc += hf[rr][j] * fcw[c * HH + j];
    lgts[rr][c] = acc;
  }
  __syncthreads();
  if (tau < RR * CC) {
    int rr = tau >> 3, c = tau & 7;
    float mx = lgts[rr][0];
#pragma unroll
    for (int j = 1; j < CC; ++j) mx = fmaxf(mx, lgts[rr][j]);
    float ssum = 0.f;
#pragma unroll
    for (int j = 0; j < CC; ++j) ssum += __expf(lgts[rr][j] - mx);
    out[(size_t)(row0 + rr) * CC + c] = __expf(lgts[rr][c] - mx) / ssum;
  }
}

extern "C" void kernel_launch(void* const* d_in, const int* in_sizes, int n_in,
                              void* d_out, int out_size, void* d_ws, size_t ws_size,
                              hipStream_t stream) {
  const float* x    = (const float*)d_in[0];
  const float* w_ih = (const float*)d_in[1];
  const float* w_hh = (const float*)d_in[2];
  const float* b_ih = (const float*)d_in[3];
  const float* b_hh = (const float*)d_in[4];
  const float* fc_w = (const float*)d_in[5];
  const float* fc_b = (const float*)d_in[6];

  _Float16* wph = (_Float16*)d_ws;
  _Float16* wpx = wph + GG * HH;

  pack_w<<<96, 256, 0, stream>>>(w_ih, w_hh, wph, wpx);
  gru_main<<<512, 512, 0, stream>>>(x, b_ih, b_hh, fc_w, fc_b, wph, wpx, (float*)d_out);
}

// Round 5
// 255.440 us; speedup vs baseline: 1.0239x; 1.0239x over previous
//
#include <hip/hip_runtime.h>
#include <hip/hip_bf16.h>

#define TT 512
#define II 46
#define HH 64
#define GG 192
#define CC 8
#define RR 8     // rows per block
#define KP 128   // fused K per gate: [h (64) | x (46, zero-padded to 64)]

typedef __attribute__((ext_vector_type(8))) _Float16 half8;
typedef __attribute__((ext_vector_type(4))) float float4v;

__device__ inline float fsigm(float xv) {
  return __builtin_amdgcn_rcpf(1.f + __expf(-xv));
}
// tanh(x) = 1 - 2/(1 + e^{2x}); saturates correctly at +-1, branch-free
__device__ inline float ftanh2(float xv) {
  float e = __expf(2.f * xv);
  return __builtin_fmaf(-2.f, __builtin_amdgcn_rcpf(1.f + e), 1.f);
}

// wp[u][k] f16, u in [0,192): k<64 -> w_hh[u][k]; 64<=k<110 -> w_ih[u][k-64]; else 0.
__global__ void pack_w(const float* __restrict__ w_ih, const float* __restrict__ w_hh,
                       _Float16* __restrict__ wp) {
  int idx = blockIdx.x * 256 + threadIdx.x;  // 192*128 = 24576 exact
  int u = idx >> 7, k = idx & 127;
  float v = (k < HH) ? w_hh[u * HH + k]
                     : ((k < HH + II) ? w_ih[u * II + (k - HH)] : 0.f);
  wp[idx] = (_Float16)v;
}

// LDS frag layouts (f16): element (row m, k) lives at [k>>5][((k>>3)&3)*16 + m][k&7];
// lane l of any wave reads its A-frag for kstep s as  frag[s][l][0..7]
// (row = l&15, k = 32*s + (l>>4)*8 + j).  hsf: k 0..63 of the fused K;
// xsf: k 64..127 (x part, indices 46..63 stay zero -> matching zero weights).
__launch_bounds__(256, 1)
__global__ void gru_main(const float* __restrict__ x,
                         const float* __restrict__ b_ih, const float* __restrict__ b_hh,
                         const float* __restrict__ fc_w, const float* __restrict__ fc_b,
                         const _Float16* __restrict__ wp,
                         float* __restrict__ out) {
  __shared__ __align__(16) _Float16 hsf[2][2][64][8];
  __shared__ __align__(16) _Float16 xsf[2][2][64][8];
  __shared__ float hf[RR][HH + 1];
  __shared__ float fcw[CC * HH];
  __shared__ float fcbs[CC];
  __shared__ float lgts[RR][CC];

  const int tau = threadIdx.x;
  const int w4  = tau >> 6;   // wave 0..3 (units 16*w4 .. 16*w4+15)
  const int l   = tau & 63;
  const int m16 = l & 15;
  const int kg  = l >> 4;
  const int row0 = blockIdx.x * RR;

  {
    _Float16* p = &hsf[0][0][0][0];
    for (int i = tau; i < 2 * 2 * 64 * 8; i += 256) p[i] = (_Float16)0.f;
    p = &xsf[0][0][0][0];
    for (int i = tau; i < 2 * 2 * 64 * 8; i += 256) p[i] = (_Float16)0.f;
  }

  const int u = 16 * w4 + m16;   // gate unit (output col) owned by this lane
  const float br  = b_ih[u] + b_hh[u];
  const float bz  = b_ih[64 + u] + b_hh[64 + u];
  const float bnx = b_ih[128 + u];
  const float bnh = b_hh[128 + u];

  // persistent B-fragments: [gate r,z,n][kstep 0..3]
  half8 bf[3][4];
#pragma unroll
  for (int g = 0; g < 3; ++g) {
    const _Float16* bb = wp + (size_t)(64 * g + u) * KP + kg * 8;
#pragma unroll
    for (int s = 0; s < 4; ++s) bf[g][s] = *(const half8*)(bb + 32 * s);
  }

  // h write-back coords (unit u, rows row0l+i)
  const int sh  = w4 >> 1;
  const int kgp = (u >> 3) & 3;
  const int jp  = u & 7;
  const int row0l = (kg & 1) * 4 + (kg >> 1) * 2;  // kg0:{0,1} kg1:{4,5} kg2:{2,3} kg3:{6,7}
  const bool lo2 = (kg < 2);

  // x staging: thread owns elements tau and tau+256 of the 8x46 slab (368 total)
  const int r1 = tau / II, i1 = tau % II;
  const bool has2 = (tau + 256) < RR * II;
  const int e2 = tau + 256;
  const int r2 = has2 ? e2 / II : r1, i2 = has2 ? e2 % II : i1;
  const float* xp1 = x + (size_t)(row0 + r1) * TT * II + i1;
  const float* xp2 = x + (size_t)(row0 + r2) * TT * II + i2;
  const int s1 = i1 >> 5, kg1 = (i1 >> 3) & 3, j1 = i1 & 7;
  const int s2 = i2 >> 5, kg2 = (i2 >> 3) & 3, j2 = i2 & 7;

  auto stageX = [&](int buf, float va, float vb) {
    xsf[buf][s1][kg1 * 16 + r1][j1] = (_Float16)va;
    if (has2) xsf[buf][s2][kg2 * 16 + r2][j2] = (_Float16)vb;
  };

  float hreg[2] = {0.f, 0.f};

  // prologue: x(0) staged now; x(1) in xc (staged at t=0); x(2) in xn
  float v0a = xp1[0],       v0b = has2 ? xp2[0] : 0.f;
  float xc1 = xp1[II],      xc2 = has2 ? xp2[II] : 0.f;
  float xn1 = xp1[2 * II],  xn2 = has2 ? xp2[2 * II] : 0.f;
  __syncthreads();           // zero-init fence
  stageX(0, v0a, v0b);

  for (int t = 0; t < TT; ++t) {
    __syncthreads();         // hsf[cur]/xsf[cur] (written last iter) ready
    const int cur = t & 1, nxt = cur ^ 1;
    half8 a0 = *(const half8*)&hsf[cur][0][l][0];
    half8 a1 = *(const half8*)&hsf[cur][1][l][0];
    half8 a2 = *(const half8*)&xsf[cur][0][l][0];
    half8 a3 = *(const half8*)&xsf[cur][1][l][0];

    float4v accr  = {br, br, br, br};
    float4v accz  = {bz, bz, bz, bz};
    float4v accnh = {bnh, bnh, bnh, bnh};
    float4v accnx = {bnx, bnx, bnx, bnx};
    accr  = __builtin_amdgcn_mfma_f32_16x16x32_f16(a0, bf[0][0], accr, 0, 0, 0);
    accr  = __builtin_amdgcn_mfma_f32_16x16x32_f16(a1, bf[0][1], accr, 0, 0, 0);
    accr  = __builtin_amdgcn_mfma_f32_16x16x32_f16(a2, bf[0][2], accr, 0, 0, 0);
    accr  = __builtin_amdgcn_mfma_f32_16x16x32_f16(a3, bf[0][3], accr, 0, 0, 0);
    accz  = __builtin_amdgcn_mfma_f32_16x16x32_f16(a0, bf[1][0], accz, 0, 0, 0);
    accz  = __builtin_amdgcn_mfma_f32_16x16x32_f16(a1, bf[1][1], accz, 0, 0, 0);
    accz  = __builtin_amdgcn_mfma_f32_16x16x32_f16(a2, bf[1][2], accz, 0, 0, 0);
    accz  = __builtin_amdgcn_mfma_f32_16x16x32_f16(a3, bf[1][3], accz, 0, 0, 0);
    accnh = __builtin_amdgcn_mfma_f32_16x16x32_f16(a0, bf[2][0], accnh, 0, 0, 0);
    accnh = __builtin_amdgcn_mfma_f32_16x16x32_f16(a1, bf[2][1], accnh, 0, 0, 0);
    accnx = __builtin_amdgcn_mfma_f32_16x16x32_f16(a2, bf[2][2], accnx, 0, 0, 0);
    accnx = __builtin_amdgcn_mfma_f32_16x16x32_f16(a3, bf[2][3], accnx, 0, 0, 0);

    // staging + prefetch (overlaps MFMA latency)
    if (t + 1 < TT) stageX(nxt, xc1, xc2);
    xc1 = xn1; xc2 = xn2;
    if (t + 3 < TT) {
      xn1 = xp1[(size_t)(t + 3) * II];
      if (has2) xn2 = xp2[(size_t)(t + 3) * II];
    }

    // redistribute acc rows 2,3 (mod 4) across the xor-32 pair:
    // every lane ends with 2 real (row,unit) gate-sets.
    float r2s = __shfl_xor(accr[2], 32),  r3s = __shfl_xor(accr[3], 32);
    float z2s = __shfl_xor(accz[2], 32),  z3s = __shfl_xor(accz[3], 32);
    float h2s = __shfl_xor(accnh[2], 32), h3s = __shfl_xor(accnh[3], 32);
    float x2s = __shfl_xor(accnx[2], 32), x3s = __shfl_xor(accnx[3], 32);
    float aR[2]  = {lo2 ? accr[0]  : r2s, lo2 ? accr[1]  : r3s};
    float aZ[2]  = {lo2 ? accz[0]  : z2s, lo2 ? accz[1]  : z3s};
    float aNH[2] = {lo2 ? accnh[0] : h2s, lo2 ? accnh[1] : h3s};
    float aNX[2] = {lo2 ? accnx[0] : x2s, lo2 ? accnx[1] : x3s};

#pragma unroll
    for (int i = 0; i < 2; ++i) {
      float rg = fsigm(aR[i]);
      float zg = fsigm(aZ[i]);
      float pre = __builtin_fmaf(rg, aNH[i], aNX[i]);
      float ng = ftanh2(pre);
      hreg[i] = ng + zg * (hreg[i] - ng);
      hsf[nxt][sh][kgp * 16 + row0l + i][jp] = (_Float16)hreg[i];
    }
  }

  // ================= Epilogue: FC + softmax =================
  hf[row0l + 0][u] = hreg[0];
  hf[row0l + 1][u] = hreg[1];
  fcw[tau] = fc_w[tau];
  fcw[tau + 256] = fc_w[tau + 256];
  if (tau < CC) fcbs[tau] = fc_b[tau];
  __syncthreads();
  if (tau < RR * CC) {
    int rr = tau >> 3, c = tau & 7;
    float acc = fcbs[c];
#pragma unroll
    for (int j = 0; j < HH; ++j) acc += hf[rr][j] * fcw[c * HH + j];
    lgts[rr][c] = acc;
  }
  __syncthreads();
  if (tau < RR * CC) {
    int rr = tau >> 3, c = tau & 7;
    float mx = lgts[rr][0];
#pragma unroll
    for (int j = 1; j < CC; ++j) mx = fmaxf(mx, lgts[rr][j]);
    float ssum = 0.f;
#pragma unroll
    for (int j = 0; j < CC; ++j) ssum += __expf(lgts[rr][j] - mx);
    out[(size_t)(row0 + rr) * CC + c] = __expf(lgts[rr][c] - mx) / ssum;
  }
}

extern "C" void kernel_launch(void* const* d_in, const int* in_sizes, int n_in,
                              void* d_out, int out_size, void* d_ws, size_t ws_size,
                              hipStream_t stream) {
  const float* x    = (const float*)d_in[0];
  const float* w_ih = (const float*)d_in[1];
  const float* w_hh = (const float*)d_in[2];
  const float* b_ih = (const float*)d_in[3];
  const float* b_hh = (const float*)d_in[4];
  const float* fc_w = (const float*)d_in[5];
  const float* fc_b = (const float*)d_in[6];

  _Float16* wp = (_Float16*)d_ws;  // 192*128 f16 = 48 KiB

  pack_w<<<96, 256, 0, stream>>>(w_ih, w_hh, wp);
  gru_main<<<256, 256, 0, stream>>>(x, b_ih, b_hh, fc_w, fc_b, wp, (float*)d_out);
}